// Round 1
// baseline (1357.986 us; speedup 1.0000x reference)
//
#include <hip/hip_runtime.h>
#include <cstdint>

// Geometry: B=8, C=512, H=37, W=50, HW=1850, BHW=14800, anchors A=16650, K1=400
#define BHW_ 14800
#define CHW_ 947200   // 512*1850
#define A_   16650
#define NOUT0 532800  // offset_pred 8*16650*4
#define OCLS 532800   // cls_pred start
#define OBOX 799200   // boxes start
#define OKEEP 812000  // keep start

__device__ __forceinline__ unsigned int fkey(float f){
  unsigned int u = __float_as_uint(f);
  return (u & 0x80000000u) ? ~u : (u | 0x80000000u);
}

// anchor half-sizes in double, exactly as numpy: w = (16*s)/sqrt(r), h = (16*s)*sqrt(r)
__device__ __forceinline__ void anchor_corners(int x, int y, int kk,
                                               float& ax1, float& ay1, float& ax2, float& ay2){
  int si = kk % 3, ri = kk / 3;
  double rv = (ri==0) ? 0.5 : ((ri==1) ? 1.0 : 2.0);
  double sr = sqrt(rv);
  double fs = 128.0 * (double)(si+1);   // 16*s, s in {8,16,24}
  double h = fs * sr, w = fs / sr;
  double cx = (double)(x*16 + 8), cy = (double)(y*16 + 8);
  ax1 = (float)(cx - w*0.5); ay1 = (float)(cy - h*0.5);
  ax2 = (float)(cx + w*0.5); ay2 = (float)(cy + h*0.5);
}

// --- repack conv weights: wpack[((khw*512)+ci)*512+o] = w[(o*512+ci)*9+khw]
__global__ __launch_bounds__(256) void k_repack_w(const float* __restrict__ w, float* __restrict__ wpack){
  int t = blockIdx.x*256 + threadIdx.x;
  if (t >= 9*512*512) return;
  int o = t & 511, ci = (t >> 9) & 511, khw = t >> 18;
  wpack[t] = w[(o*512 + ci)*9 + khw];
}

// --- pack head weights [ci][64]: rows 0-17 cls, 18-53 off, 54-63 zero
__global__ __launch_bounds__(256) void k_pack_heads(const float* __restrict__ cw, const float* __restrict__ cb,
                                                    const float* __restrict__ ow, const float* __restrict__ ob,
                                                    float* __restrict__ hwp, float* __restrict__ hb){
  int t = blockIdx.x*256 + threadIdx.x;
  if (t < 64) hb[t] = (t < 18) ? cb[t] : (t < 54 ? ob[t-18] : 0.f);
  if (t >= 512*64) return;
  int r = t & 63, ci = t >> 6;
  hwp[t] = (r < 18) ? cw[r*512 + ci] : (r < 54 ? ow[(r-18)*512 + ci] : 0.f);
}

// --- 3x3 conv as 9 accumulated GEMMs. BM=64(out-ch) BN=64(pos) BK=16, 256 thr, 4x4 microtile
__global__ __launch_bounds__(256) void k_conv3(const float* __restrict__ feat, const float* __restrict__ wpack,
                                               const float* __restrict__ mdb, float* __restrict__ out0){
  __shared__ float As[16][64];
  __shared__ float Bs[16][64];
  __shared__ int sb[64], sy[64], sx[64];
  int tid = threadIdx.x;
  int ntile = blockIdx.x, otile = blockIdx.y;
  if (tid < 64){
    int n = ntile*64 + tid;
    if (n < BHW_){ int b = n/1850; int r = n - b*1850; int y = r/50; sb[tid]=b; sy[tid]=y; sx[tid]=r - y*50; }
    else { sb[tid] = -1; sy[tid] = 0; sx[tid] = 0; }
  }
  __syncthreads();
  float acc[4][4] = {};
  const int tx = tid & 15, ty = tid >> 4;
  const int lci = tid >> 4;         // staging row 0..15
  const int lo4 = (tid & 15) * 4;   // staging col*4
  for (int khw = 0; khw < 9; ++khw){
    int kh = khw/3;
    int dy = kh - 1, dx = (khw - kh*3) - 1;
    const float* wsrc = wpack + khw*(512*512);
    for (int ct = 0; ct < 32; ++ct){
      int cib = ct*16;
      float4 av = *(const float4*)(wsrc + (cib + lci)*512 + otile*64 + lo4);
      float4 bv; float* bp = (float*)&bv;
      int cig = cib + lci;
      #pragma unroll
      for (int j = 0; j < 4; ++j){
        int nn = lo4 + j;
        int b = sb[nn]; int yy = sy[nn] + dy; int xx = sx[nn] + dx;
        float v = 0.f;
        if (b >= 0 && (unsigned)yy < 37u && (unsigned)xx < 50u)
          v = feat[b*CHW_ + cig*1850 + yy*50 + xx];
        bp[j] = v;
      }
      __syncthreads();
      *(float4*)&As[lci][lo4] = av;
      *(float4*)&Bs[lci][lo4] = bv;
      __syncthreads();
      #pragma unroll
      for (int k = 0; k < 16; ++k){
        float4 a4 = *(const float4*)&As[k][ty*4];
        float4 b4 = *(const float4*)&Bs[k][tx*4];
        const float* ap = (const float*)&a4; const float* bq = (const float*)&b4;
        #pragma unroll
        for (int i = 0; i < 4; ++i)
          #pragma unroll
          for (int j = 0; j < 4; ++j)
            acc[i][j] = fmaf(ap[i], bq[j], acc[i][j]);
      }
    }
  }
  #pragma unroll
  for (int i = 0; i < 4; ++i){
    int o = otile*64 + ty*4 + i;
    float bias = mdb[o];
    #pragma unroll
    for (int j = 0; j < 4; ++j){
      int nl = tx*4 + j;
      int b = sb[nl];
      if (b >= 0)
        out0[b*CHW_ + o*1850 + sy[nl]*50 + sx[nl]] = acc[i][j] + bias;
    }
  }
}

// --- BN stats per channel (double accumulation)
__global__ __launch_bounds__(256) void k_bnstats(const float* __restrict__ out0,
                                                 float* __restrict__ bnm, float* __restrict__ bnr){
  __shared__ double s1[256], s2[256];
  int c = blockIdx.x, tid = threadIdx.x;
  double a = 0.0, b = 0.0;
  for (int i = tid; i < BHW_; i += 256){
    int bb = i / 1850; int r = i - bb*1850;
    float v = out0[bb*CHW_ + c*1850 + r];
    a += (double)v; b += (double)v*(double)v;
  }
  s1[tid] = a; s2[tid] = b; __syncthreads();
  for (int off = 128; off; off >>= 1){
    if (tid < off){ s1[tid] += s1[tid+off]; s2[tid] += s2[tid+off]; }
    __syncthreads();
  }
  if (tid == 0){
    double m = s1[0] / 14800.0;
    double var = s2[0] / 14800.0 - m*m;
    bnm[c] = (float)m;
    bnr[c] = 1.0f / sqrtf((float)var + 1e-5f);
  }
}

// --- BN apply + ReLU in place
__global__ __launch_bounds__(256) void k_bnrelu(float* __restrict__ out0, const float* __restrict__ bnm,
                                                const float* __restrict__ bnr, const float* __restrict__ gamma,
                                                const float* __restrict__ beta){
#pragma clang fp contract(off)
  int g = blockIdx.x*256 + threadIdx.x;
  if (g >= 8*CHW_) return;
  int c = (g / 1850) & 511;
  float x = out0[g];
  float y = gamma[c] * (x - bnm[c]);
  y = y * bnr[c];
  y = y + beta[c];
  out0[g] = fmaxf(y, 0.f);
}

// --- head GEMM: 64 rows x 14800 pos, K=512; scatter into d_out transposed layouts
__global__ __launch_bounds__(256) void k_heads(const float* __restrict__ out0, const float* __restrict__ hwp,
                                               const float* __restrict__ hb, float* __restrict__ dout){
  __shared__ float As[16][64];
  __shared__ float Bs[16][64];
  __shared__ int sb[64], sy[64], sx[64];
  int tid = threadIdx.x; int ntile = blockIdx.x;
  if (tid < 64){
    int n = ntile*64 + tid;
    if (n < BHW_){ int b = n/1850; int r = n - b*1850; int y = r/50; sb[tid]=b; sy[tid]=y; sx[tid]=r - y*50; }
    else { sb[tid] = -1; sy[tid] = 0; sx[tid] = 0; }
  }
  __syncthreads();
  float acc[4][4] = {};
  const int tx = tid & 15, ty = tid >> 4;
  const int lci = tid >> 4, lo4 = (tid & 15) * 4;
  for (int ct = 0; ct < 32; ++ct){
    int cib = ct*16;
    float4 av = *(const float4*)(hwp + (cib + lci)*64 + lo4);
    float4 bv; float* bp = (float*)&bv;
    int cig = cib + lci;
    #pragma unroll
    for (int j = 0; j < 4; ++j){
      int nn = lo4 + j; int b = sb[nn];
      bp[j] = (b >= 0) ? out0[b*CHW_ + cig*1850 + sy[nn]*50 + sx[nn]] : 0.f;
    }
    __syncthreads();
    *(float4*)&As[lci][lo4] = av;
    *(float4*)&Bs[lci][lo4] = bv;
    __syncthreads();
    #pragma unroll
    for (int k = 0; k < 16; ++k){
      float4 a4 = *(const float4*)&As[k][ty*4];
      float4 b4 = *(const float4*)&Bs[k][tx*4];
      const float* ap = (const float*)&a4; const float* bq = (const float*)&b4;
      #pragma unroll
      for (int i = 0; i < 4; ++i)
        #pragma unroll
        for (int j = 0; j < 4; ++j)
          acc[i][j] = fmaf(ap[i], bq[j], acc[i][j]);
    }
  }
  #pragma unroll
  for (int i = 0; i < 4; ++i){
    int r = ty*4 + i;
    if (r >= 54) continue;
    float bias = hb[r];
    #pragma unroll
    for (int j = 0; j < 4; ++j){
      int nl = tx*4 + j;
      int b = sb[nl];
      if (b < 0) continue;
      int pos = sy[nl]*50 + sx[nl];
      float v = acc[i][j] + bias;
      if (r < 18){
        int kk = r >> 1, cc = r & 1;
        dout[OCLS + (b*A_ + pos*9 + kk)*2 + cc] = v;
      } else {
        int r2 = r - 18, kk = r2 >> 2, cc = r2 & 3;
        dout[(b*A_ + pos*9 + kk)*4 + cc] = v;
      }
    }
  }
}

// --- per-anchor sortable key (valid anchors only); score order == order of (c1-c0)
__global__ __launch_bounds__(256) void k_score(const float* __restrict__ dout, unsigned long long* __restrict__ keys){
  int g = blockIdx.x*256 + threadIdx.x;
  if (g >= 8*A_) return;
  int b = g / A_; int a = g - b*A_;
  int pos = a / 9; int kk = a - pos*9;
  int y = pos / 50; int x = pos - y*50;
  float ax1, ay1, ax2, ay2;
  anchor_corners(x, y, kk, ax1, ay1, ax2, ay2);
  bool valid = (ax1 >= 0.f) && (ay1 >= 0.f) && (ax2 < 800.f) && (ay2 < 592.f);
  unsigned long long key = 0ull;
  if (valid){
    float c0 = dout[OCLS + (b*A_ + a)*2 + 0];
    float c1 = dout[OCLS + (b*A_ + a)*2 + 1];
    float d = c1 - c0;
    key = ((unsigned long long)fkey(d) << 32) | (unsigned long long)(~(unsigned int)a);
  }
  keys[g] = key;
}

// --- histogram cutoff + candidate compaction (per batch)
__global__ __launch_bounds__(1024) void k_select(const unsigned long long* __restrict__ keys,
                                                 unsigned long long* __restrict__ cand, unsigned int* __restrict__ ccnt){
  __shared__ unsigned int bins[4096];
  __shared__ unsigned int sp[1024];
  __shared__ unsigned int sbstar;
  __shared__ unsigned int scnt;
  int b = blockIdx.x, tid = threadIdx.x;
  const unsigned long long* kb = keys + b*A_;
  for (int i = tid; i < 4096; i += 1024) bins[i] = 0u;
  if (tid == 0) scnt = 0u;
  __syncthreads();
  for (int i = tid; i < A_; i += 1024){
    unsigned long long k = kb[i];
    if (k) atomicAdd(&bins[(unsigned int)(k >> 52)], 1u);
  }
  __syncthreads();
  unsigned int p = bins[tid*4] + bins[tid*4+1] + bins[tid*4+2] + bins[tid*4+3];
  sp[tid] = p; __syncthreads();
  for (int off = 1; off < 1024; off <<= 1){
    unsigned int v = sp[tid] + ((tid + off < 1024) ? sp[tid + off] : 0u);
    __syncthreads(); sp[tid] = v; __syncthreads();
  }
  if (sp[tid] >= 400u && (tid == 1023 || sp[tid+1] < 400u)){
    unsigned int base = (tid == 1023) ? 0u : sp[tid+1];
    unsigned int cum = base; int bs = tid*4;
    for (int bb = tid*4 + 3; bb >= tid*4; --bb){
      cum += bins[bb];
      if (cum >= 400u){ bs = bb; break; }
    }
    sbstar = (unsigned int)bs;
  }
  __syncthreads();
  unsigned int bstar = sbstar;
  for (int i = tid; i < A_; i += 1024){
    unsigned long long k = kb[i];
    if (k && (unsigned int)(k >> 52) >= bstar){
      unsigned int pidx = atomicAdd(&scnt, 1u);
      cand[b*A_ + pidx] = k;
    }
  }
  __syncthreads();
  if (tid == 0) ccnt[b] = scnt;
}

// --- exact rank-by-counting among candidates -> ordered top-400 keys
__global__ __launch_bounds__(1024) void k_rank(const unsigned long long* __restrict__ cand,
                                               const unsigned int* __restrict__ ccnt,
                                               unsigned long long* __restrict__ topk){
  __shared__ unsigned long long ch[2048];
  int b = blockIdx.x, tid = threadIdx.x;
  int C = (int)ccnt[b];
  const unsigned long long* cb = cand + b*A_;
  unsigned long long mk[17]; int mc[17]; int nm = 0;
  for (int i = tid; i < C; i += 1024){ mk[nm] = cb[i]; mc[nm] = 0; ++nm; }
  for (int base = 0; base < C; base += 2048){
    int lim = min(2048, C - base);
    __syncthreads();
    for (int i = tid; i < lim; i += 1024) ch[i] = cb[base + i];
    __syncthreads();
    for (int t = 0; t < nm; ++t){
      unsigned long long my = mk[t]; int cc = 0;
      for (int j = 0; j < lim; ++j) cc += (ch[j] > my) ? 1 : 0;
      mc[t] += cc;
    }
  }
  for (int t = 0; t < nm; ++t)
    if (mc[t] < 400) topk[b*400 + mc[t]] = mk[t];
}

// --- decode boxes (write out) + greedy NMS on truncated boxes -> keep
__global__ __launch_bounds__(512) void k_nms(const unsigned long long* __restrict__ topk,
                                             float* __restrict__ dout){
#pragma clang fp contract(off)
  __shared__ float X1[400], Y1[400], X2[400], Y2[400], AR[400];
  __shared__ bool SUP[400];
  int b = blockIdx.x, tid = threadIdx.x;
  if (tid < 400){
    unsigned long long key = topk[b*400 + tid];
    unsigned int a = ~(unsigned int)(key & 0xFFFFFFFFull);
    int pos = a / 9; int kk = a - pos*9;
    int y = pos / 50; int x = pos - y*50;
    float ax1, ay1, ax2, ay2;
    anchor_corners(x, y, (int)kk, ax1, ay1, ax2, ay2);
    float xa = (ax1 + ax2) * 0.5f;
    float ya = (ay1 + ay2) * 0.5f;
    float wa = ax2 - ax1 + 1.0f;
    float ha = ay2 - ay1 + 1.0f;
    const float* t = dout + (b*A_ + a)*4;
    float t0 = t[0], t1 = t[1], t2 = t[2], t3 = t[3];
    float xc = t0 * wa + xa;
    float yc = t1 * ha + ya;
    float bw = wa * expf(t2);
    float bh = ha * expf(t3);
    float bx1 = xc - bw*0.5f, by1 = yc - bh*0.5f;
    float bx2 = xc + bw*0.5f, by2 = yc + bh*0.5f;
    float* bo = dout + OBOX + (b*400 + tid)*4;
    bo[0] = bx1; bo[1] = by1; bo[2] = bx2; bo[3] = by2;
    float tx1 = truncf(bx1), ty1 = truncf(by1), tx2 = truncf(bx2), ty2 = truncf(by2);
    X1[tid] = tx1; Y1[tid] = ty1; X2[tid] = tx2; Y2[tid] = ty2;
    AR[tid] = (tx2 - tx1 + 1.0f) * (ty2 - ty1 + 1.0f);
    SUP[tid] = false;
  }
  __syncthreads();
  for (int i = 0; i < 399; ++i){
    bool alive = !SUP[i];
    if (alive && tid > i && tid < 400){
      float iw = fminf(X2[i], X2[tid]) - fmaxf(X1[i], X1[tid]) + 1.0f; iw = fmaxf(iw, 0.f);
      float ih = fminf(Y2[i], Y2[tid]) - fmaxf(Y1[i], Y1[tid]) + 1.0f; ih = fmaxf(ih, 0.f);
      float inter = iw * ih;
      float iou = inter / ((AR[i] + AR[tid]) - inter);
      if (iou > 0.6f) SUP[tid] = true;
    }
    __syncthreads();
  }
  if (tid < 400) dout[OKEEP + b*400 + tid] = SUP[tid] ? 0.f : 1.f;
}

extern "C" void kernel_launch(void* const* d_in, const int* in_sizes, int n_in,
                              void* d_out, int out_size, void* d_ws, size_t ws_size,
                              hipStream_t stream){
  const float* feat  = (const float*)d_in[0];
  const float* mdw   = (const float*)d_in[1];
  const float* mdb   = (const float*)d_in[2];
  const float* gamma = (const float*)d_in[3];
  const float* beta  = (const float*)d_in[4];
  const float* clsw  = (const float*)d_in[5];
  const float* clsb  = (const float*)d_in[6];
  const float* offw  = (const float*)d_in[7];
  const float* offb  = (const float*)d_in[8];
  float* dout = (float*)d_out;
  float* ws = (float*)d_ws;

  float* out0  = ws;                     // 7,577,600
  float* wpack = out0 + 7577600;         // 2,359,296
  float* hwp   = wpack + 2359296;        // 32,768
  float* hb    = hwp + 32768;            // 64
  float* bnm   = hb + 64;                // 512
  float* bnr   = bnm + 512;              // 512
  unsigned long long* keys = (unsigned long long*)(bnr + 512);  // 133,200 u64
  unsigned long long* cand = keys + 133200;                     // 133,200 u64
  unsigned long long* topk = cand + 133200;                     // 3,200 u64
  unsigned int* ccnt = (unsigned int*)(topk + 3200);            // 8 u32
  // total ws use: ~42.1 MB

  k_repack_w<<<dim3(9216), 256, 0, stream>>>(mdw, wpack);
  k_pack_heads<<<dim3(128), 256, 0, stream>>>(clsw, clsb, offw, offb, hwp, hb);
  k_conv3<<<dim3(232, 8), 256, 0, stream>>>(feat, wpack, mdb, out0);
  k_bnstats<<<dim3(512), 256, 0, stream>>>(out0, bnm, bnr);
  k_bnrelu<<<dim3(29600), 256, 0, stream>>>(out0, bnm, bnr, gamma, beta);
  k_heads<<<dim3(232), 256, 0, stream>>>(out0, hwp, hb, dout);
  k_score<<<dim3(521), 256, 0, stream>>>(dout, keys);
  k_select<<<dim3(8), 1024, 0, stream>>>(keys, cand, ccnt);
  k_rank<<<dim3(8), 1024, 0, stream>>>(cand, ccnt, topk);
  k_nms<<<dim3(8), 512, 0, stream>>>(topk, dout);
}

// Round 2
// 458.102 us; speedup vs baseline: 2.9644x; 2.9644x over previous
//
#include <hip/hip_runtime.h>
#include <cstdint>

// Geometry: B=8, C=512, H=37, W=50, HW=1850, BHW=14800, anchors A=16650, K1=400
#define BHW_ 14800
#define CHW_ 947200   // 512*1850
#define A_   16650
#define OCLS 532800   // cls_pred start
#define OBOX 799200   // boxes start
#define OKEEP 812000  // keep start

typedef _Float16 f16x8 __attribute__((ext_vector_type(8)));
typedef float f32x4 __attribute__((ext_vector_type(4)));

__device__ __forceinline__ unsigned int fkey(float f){
  unsigned int u = __float_as_uint(f);
  return (u & 0x80000000u) ? ~u : (u | 0x80000000u);
}

// anchor half-sizes in double, exactly as numpy: w = (16*s)/sqrt(r), h = (16*s)*sqrt(r)
__device__ __forceinline__ void anchor_corners(int x, int y, int kk,
                                               float& ax1, float& ay1, float& ax2, float& ay2){
  int si = kk % 3, ri = kk / 3;
  double rv = (ri==0) ? 0.5 : ((ri==1) ? 1.0 : 2.0);
  double sr = sqrt(rv);
  double fs = 128.0 * (double)(si+1);   // 16*s, s in {8,16,24}
  double h = fs * sr, w = fs / sr;
  double cx = (double)(x*16 + 8), cy = (double)(y*16 + 8);
  ax1 = (float)(cx - w*0.5); ay1 = (float)(cy - h*0.5);
  ax2 = (float)(cx + w*0.5); ay2 = (float)(cy + h*0.5);
}

// --- repack conv weights for (cc outer, khw inner) K-order:
// wpack2[((cc*9 + khw)*32 + cin)*512 + o] = w[(o*512 + cc*32 + cin)*9 + khw]
__global__ __launch_bounds__(256) void k_repack_w(const float* __restrict__ w, float* __restrict__ wpack2){
  int t = blockIdx.x*256 + threadIdx.x;
  if (t >= 9*512*512) return;
  int o = t & 511;
  int u = t >> 9;          // 0..4607 = (cc*9+khw)*32 + cin
  int cin = u & 31;
  int v2 = u >> 5;         // 0..143
  int khw = v2 % 9;
  int cc  = v2 / 9;
  wpack2[t] = w[(o*512 + cc*32 + cin)*9 + khw];
}

// --- pack head weights [ci][64]: rows 0-17 cls, 18-53 off, 54-63 zero
__global__ __launch_bounds__(256) void k_pack_heads(const float* __restrict__ cw, const float* __restrict__ cb,
                                                    const float* __restrict__ ow, const float* __restrict__ ob,
                                                    float* __restrict__ hwp, float* __restrict__ hb){
  int t = blockIdx.x*256 + threadIdx.x;
  if (t < 64) hb[t] = (t < 18) ? cb[t] : (t < 54 ? ob[t-18] : 0.f);
  if (t >= 512*64) return;
  int r = t & 63, ci = t >> 6;
  hwp[t] = (r < 18) ? cw[r*512 + ci] : (r < 54 ? ow[(r-18)*512 + ci] : 0.f);
}

// --- 3x3 conv as implicit GEMM with fp16x2-split MFMA.
// M=512 (o), N=14800 (pos), K=4608 (cc 0..15 outer, khw 0..8 inner, ci 32 per step).
// BM=128, BN=128, BK=32, 256 threads = 4 waves (2x2 of 64x64).
__global__ __launch_bounds__(256) void k_conv3_mfma(const float* __restrict__ feat,
                                                    const float* __restrict__ wpack2,
                                                    const float* __restrict__ mdb,
                                                    float* __restrict__ out0){
  __shared__ _Float16 Ah[4][128][8];
  __shared__ _Float16 Al[4][128][8];
  __shared__ _Float16 Bh[4][128][8];
  __shared__ _Float16 Bl[4][128][8];

  const int tid = threadIdx.x;
  // bijective XCD swizzle: 464 blocks = 8 XCDs * 58
  int flat = blockIdx.x;
  int xcd = flat & 7, sub = flat >> 3;
  int swz = xcd * 58 + sub;
  int otile = swz / 116;            // 0..3
  int ntile = swz - otile*116;      // 0..115

  // staging role: 128 m/n columns x 2 k-groups of 16
  const int cpos = tid & 127;       // m for A, n for B
  const int kg   = tid >> 7;        // 0..1 -> k = kg*16 + i

  // decode this thread's B position once
  int n = ntile*128 + cpos;
  bool nvalid = n < BHW_;
  int nb = 0, ny = 0, nx = 0;
  if (nvalid){ nb = n/1850; int rem = n - nb*1850; ny = rem/50; nx = rem - ny*50; }

  float av[16], bv[16];

  // load step s into registers
  auto loadAB = [&](int s){
    int cc = s / 9, khw = s - cc*9;
    const float* asrc = wpack2 + (size_t)(((cc*9 + khw)*32 + kg*16))*512 + otile*128 + cpos;
    #pragma unroll
    for (int i = 0; i < 16; ++i) av[i] = asrc[i*512];
    int dy = khw/3 - 1, dx = (khw - (khw/3)*3) - 1;
    int yy = ny + dy, xx = nx + dx;
    bool v = nvalid && ((unsigned)yy < 37u) && ((unsigned)xx < 50u);
    const float* bsrc = feat + (size_t)nb*CHW_ + (size_t)(cc*32 + kg*16)*1850 + yy*50 + xx;
    #pragma unroll
    for (int i = 0; i < 16; ++i) bv[i] = v ? bsrc[i*1850] : 0.f;
  };

  // split regs -> LDS
  auto writeAB = [&](){
    #pragma unroll
    for (int g = 0; g < 2; ++g){
      f16x8 ah, al, bh, bl;
      #pragma unroll
      for (int j = 0; j < 8; ++j){
        float va = av[g*8 + j];
        _Float16 ha = (_Float16)va;
        ah[j] = ha; al[j] = (_Float16)(va - (float)ha);
        float vb = bv[g*8 + j];
        _Float16 hb2 = (_Float16)vb;
        bh[j] = hb2; bl[j] = (_Float16)(vb - (float)hb2);
      }
      int gg = kg*2 + g;
      *(f16x8*)&Ah[gg][cpos][0] = ah;
      *(f16x8*)&Al[gg][cpos][0] = al;
      *(f16x8*)&Bh[gg][cpos][0] = bh;
      *(f16x8*)&Bl[gg][cpos][0] = bl;
    }
  };

  // compute role
  const int w   = tid >> 6;
  const int lane = tid & 63;
  const int wm = w >> 1, wn = w & 1;
  const int l15 = lane & 15, l4 = lane >> 4;

  f32x4 acc[4][4] = {};

  loadAB(0);
  for (int s = 0; s < 144; ++s){
    __syncthreads();              // previous compute done; LDS writable
    writeAB();
    if (s + 1 < 144) loadAB(s + 1);   // prefetch next step; overlaps MFMA below
    __syncthreads();              // staged tile visible

    f16x8 af[4][2], bf[4][2];
    #pragma unroll
    for (int mf = 0; mf < 4; ++mf){
      int m = wm*64 + mf*16 + l15;
      af[mf][0] = *(const f16x8*)&Ah[l4][m][0];
      af[mf][1] = *(const f16x8*)&Al[l4][m][0];
    }
    #pragma unroll
    for (int nf = 0; nf < 4; ++nf){
      int nn = wn*64 + nf*16 + l15;
      bf[nf][0] = *(const f16x8*)&Bh[l4][nn][0];
      bf[nf][1] = *(const f16x8*)&Bl[l4][nn][0];
    }
    #pragma unroll
    for (int mf = 0; mf < 4; ++mf)
      #pragma unroll
      for (int nf = 0; nf < 4; ++nf){
        acc[mf][nf] = __builtin_amdgcn_mfma_f32_16x16x32_f16(af[mf][0], bf[nf][0], acc[mf][nf], 0, 0, 0);
        acc[mf][nf] = __builtin_amdgcn_mfma_f32_16x16x32_f16(af[mf][0], bf[nf][1], acc[mf][nf], 0, 0, 0);
        acc[mf][nf] = __builtin_amdgcn_mfma_f32_16x16x32_f16(af[mf][1], bf[nf][0], acc[mf][nf], 0, 0, 0);
      }
  }

  // epilogue: D row m = l4*4 + r, col n = l15 within each 16x16 frag
  #pragma unroll
  for (int nf = 0; nf < 4; ++nf){
    int ng = ntile*128 + wn*64 + nf*16 + l15;
    if (ng >= BHW_) continue;
    int b2 = ng/1850; int rem2 = ng - b2*1850;
    #pragma unroll
    for (int mf = 0; mf < 4; ++mf){
      int o0 = otile*128 + wm*64 + mf*16 + l4*4;
      #pragma unroll
      for (int r = 0; r < 4; ++r){
        out0[(size_t)b2*CHW_ + (size_t)(o0 + r)*1850 + rem2] = acc[mf][nf][r] + mdb[o0 + r];
      }
    }
  }
}

// --- BN stats per channel (double accumulation)
__global__ __launch_bounds__(256) void k_bnstats(const float* __restrict__ out0,
                                                 float* __restrict__ bnm, float* __restrict__ bnr){
  __shared__ double s1[256], s2[256];
  int c = blockIdx.x, tid = threadIdx.x;
  double a = 0.0, b = 0.0;
  for (int i = tid; i < BHW_; i += 256){
    int bb = i / 1850; int r = i - bb*1850;
    float v = out0[bb*CHW_ + c*1850 + r];
    a += (double)v; b += (double)v*(double)v;
  }
  s1[tid] = a; s2[tid] = b; __syncthreads();
  for (int off = 128; off; off >>= 1){
    if (tid < off){ s1[tid] += s1[tid+off]; s2[tid] += s2[tid+off]; }
    __syncthreads();
  }
  if (tid == 0){
    double m = s1[0] / 14800.0;
    double var = s2[0] / 14800.0 - m*m;
    bnm[c] = (float)m;
    bnr[c] = 1.0f / sqrtf((float)var + 1e-5f);
  }
}

// --- BN apply + ReLU in place
__global__ __launch_bounds__(256) void k_bnrelu(float* __restrict__ out0, const float* __restrict__ bnm,
                                                const float* __restrict__ bnr, const float* __restrict__ gamma,
                                                const float* __restrict__ beta){
#pragma clang fp contract(off)
  int g = blockIdx.x*256 + threadIdx.x;
  if (g >= 8*CHW_) return;
  int c = (g / 1850) & 511;
  float x = out0[g];
  float y = gamma[c] * (x - bnm[c]);
  y = y * bnr[c];
  y = y + beta[c];
  out0[g] = fmaxf(y, 0.f);
}

// --- head GEMM: 64 rows x 14800 pos, K=512; scatter into d_out transposed layouts
__global__ __launch_bounds__(256) void k_heads(const float* __restrict__ out0, const float* __restrict__ hwp,
                                               const float* __restrict__ hb, float* __restrict__ dout){
  __shared__ float As[16][64];
  __shared__ float Bs[16][64];
  __shared__ int sb[64], sy[64], sx[64];
  int tid = threadIdx.x; int ntile = blockIdx.x;
  if (tid < 64){
    int n = ntile*64 + tid;
    if (n < BHW_){ int b = n/1850; int r = n - b*1850; int y = r/50; sb[tid]=b; sy[tid]=y; sx[tid]=r - y*50; }
    else { sb[tid] = -1; sy[tid] = 0; sx[tid] = 0; }
  }
  __syncthreads();
  float acc[4][4] = {};
  const int tx = tid & 15, ty = tid >> 4;
  const int lci = tid >> 4, lo4 = (tid & 15) * 4;
  for (int ct = 0; ct < 32; ++ct){
    int cib = ct*16;
    float4 av = *(const float4*)(hwp + (cib + lci)*64 + lo4);
    float4 bv; float* bp = (float*)&bv;
    int cig = cib + lci;
    #pragma unroll
    for (int j = 0; j < 4; ++j){
      int nn = lo4 + j; int b = sb[nn];
      bp[j] = (b >= 0) ? out0[b*CHW_ + cig*1850 + sy[nn]*50 + sx[nn]] : 0.f;
    }
    __syncthreads();
    *(float4*)&As[lci][lo4] = av;
    *(float4*)&Bs[lci][lo4] = bv;
    __syncthreads();
    #pragma unroll
    for (int k = 0; k < 16; ++k){
      float4 a4 = *(const float4*)&As[k][ty*4];
      float4 b4 = *(const float4*)&Bs[k][tx*4];
      const float* ap = (const float*)&a4; const float* bq = (const float*)&b4;
      #pragma unroll
      for (int i = 0; i < 4; ++i)
        #pragma unroll
        for (int j = 0; j < 4; ++j)
          acc[i][j] = fmaf(ap[i], bq[j], acc[i][j]);
    }
  }
  #pragma unroll
  for (int i = 0; i < 4; ++i){
    int r = ty*4 + i;
    if (r >= 54) continue;
    float bias = hb[r];
    #pragma unroll
    for (int j = 0; j < 4; ++j){
      int nl = tx*4 + j;
      int b = sb[nl];
      if (b < 0) continue;
      int pos = sy[nl]*50 + sx[nl];
      float v = acc[i][j] + bias;
      if (r < 18){
        int kk = r >> 1, cc = r & 1;
        dout[OCLS + (b*A_ + pos*9 + kk)*2 + cc] = v;
      } else {
        int r2 = r - 18, kk = r2 >> 2, cc = r2 & 3;
        dout[(b*A_ + pos*9 + kk)*4 + cc] = v;
      }
    }
  }
}

// --- per-anchor sortable key (valid anchors only); score order == order of (c1-c0)
__global__ __launch_bounds__(256) void k_score(const float* __restrict__ dout, unsigned long long* __restrict__ keys){
  int g = blockIdx.x*256 + threadIdx.x;
  if (g >= 8*A_) return;
  int b = g / A_; int a = g - b*A_;
  int pos = a / 9; int kk = a - pos*9;
  int y = pos / 50; int x = pos - y*50;
  float ax1, ay1, ax2, ay2;
  anchor_corners(x, y, kk, ax1, ay1, ax2, ay2);
  bool valid = (ax1 >= 0.f) && (ay1 >= 0.f) && (ax2 < 800.f) && (ay2 < 592.f);
  unsigned long long key = 0ull;
  if (valid){
    float c0 = dout[OCLS + (b*A_ + a)*2 + 0];
    float c1 = dout[OCLS + (b*A_ + a)*2 + 1];
    float d = c1 - c0;
    key = ((unsigned long long)fkey(d) << 32) | (unsigned long long)(~(unsigned int)a);
  }
  keys[g] = key;
}

// --- histogram cutoff + candidate compaction (per batch)
__global__ __launch_bounds__(1024) void k_select(const unsigned long long* __restrict__ keys,
                                                 unsigned long long* __restrict__ cand, unsigned int* __restrict__ ccnt){
  __shared__ unsigned int bins[4096];
  __shared__ unsigned int sp[1024];
  __shared__ unsigned int sbstar;
  __shared__ unsigned int scnt;
  int b = blockIdx.x, tid = threadIdx.x;
  const unsigned long long* kb = keys + b*A_;
  for (int i = tid; i < 4096; i += 1024) bins[i] = 0u;
  if (tid == 0) scnt = 0u;
  __syncthreads();
  for (int i = tid; i < A_; i += 1024){
    unsigned long long k = kb[i];
    if (k) atomicAdd(&bins[(unsigned int)(k >> 52)], 1u);
  }
  __syncthreads();
  unsigned int p = bins[tid*4] + bins[tid*4+1] + bins[tid*4+2] + bins[tid*4+3];
  sp[tid] = p; __syncthreads();
  for (int off = 1; off < 1024; off <<= 1){
    unsigned int v = sp[tid] + ((tid + off < 1024) ? sp[tid + off] : 0u);
    __syncthreads(); sp[tid] = v; __syncthreads();
  }
  if (sp[tid] >= 400u && (tid == 1023 || sp[tid+1] < 400u)){
    unsigned int base = (tid == 1023) ? 0u : sp[tid+1];
    unsigned int cum = base; int bs = tid*4;
    for (int bb = tid*4 + 3; bb >= tid*4; --bb){
      cum += bins[bb];
      if (cum >= 400u){ bs = bb; break; }
    }
    sbstar = (unsigned int)bs;
  }
  __syncthreads();
  unsigned int bstar = sbstar;
  for (int i = tid; i < A_; i += 1024){
    unsigned long long k = kb[i];
    if (k && (unsigned int)(k >> 52) >= bstar){
      unsigned int pidx = atomicAdd(&scnt, 1u);
      cand[b*A_ + pidx] = k;
    }
  }
  __syncthreads();
  if (tid == 0) ccnt[b] = scnt;
}

// --- exact rank-by-counting among candidates -> ordered top-400 keys
__global__ __launch_bounds__(1024) void k_rank(const unsigned long long* __restrict__ cand,
                                               const unsigned int* __restrict__ ccnt,
                                               unsigned long long* __restrict__ topk){
  __shared__ unsigned long long ch[2048];
  int b = blockIdx.x, tid = threadIdx.x;
  int C = (int)ccnt[b];
  const unsigned long long* cb = cand + b*A_;
  unsigned long long mk[17]; int mc[17]; int nm = 0;
  for (int i = tid; i < C; i += 1024){ mk[nm] = cb[i]; mc[nm] = 0; ++nm; }
  for (int base = 0; base < C; base += 2048){
    int lim = min(2048, C - base);
    __syncthreads();
    for (int i = tid; i < lim; i += 1024) ch[i] = cb[base + i];
    __syncthreads();
    for (int t = 0; t < nm; ++t){
      unsigned long long my = mk[t]; int cc = 0;
      for (int j = 0; j < lim; ++j) cc += (ch[j] > my) ? 1 : 0;
      mc[t] += cc;
    }
  }
  for (int t = 0; t < nm; ++t)
    if (mc[t] < 400) topk[b*400 + mc[t]] = mk[t];
}

// --- decode boxes (write out) + greedy NMS on truncated boxes -> keep
__global__ __launch_bounds__(512) void k_nms(const unsigned long long* __restrict__ topk,
                                             float* __restrict__ dout){
#pragma clang fp contract(off)
  __shared__ float X1[400], Y1[400], X2[400], Y2[400], AR[400];
  __shared__ bool SUP[400];
  int b = blockIdx.x, tid = threadIdx.x;
  if (tid < 400){
    unsigned long long key = topk[b*400 + tid];
    unsigned int a = ~(unsigned int)(key & 0xFFFFFFFFull);
    int pos = a / 9; int kk = a - pos*9;
    int y = pos / 50; int x = pos - y*50;
    float ax1, ay1, ax2, ay2;
    anchor_corners(x, y, (int)kk, ax1, ay1, ax2, ay2);
    float xa = (ax1 + ax2) * 0.5f;
    float ya = (ay1 + ay2) * 0.5f;
    float wa = ax2 - ax1 + 1.0f;
    float ha = ay2 - ay1 + 1.0f;
    const float* t = dout + (b*A_ + a)*4;
    float t0 = t[0], t1 = t[1], t2 = t[2], t3 = t[3];
    float xc = t0 * wa + xa;
    float yc = t1 * ha + ya;
    float bw = wa * expf(t2);
    float bh = ha * expf(t3);
    float bx1 = xc - bw*0.5f, by1 = yc - bh*0.5f;
    float bx2 = xc + bw*0.5f, by2 = yc + bh*0.5f;
    float* bo = dout + OBOX + (b*400 + tid)*4;
    bo[0] = bx1; bo[1] = by1; bo[2] = bx2; bo[3] = by2;
    float tx1 = truncf(bx1), ty1 = truncf(by1), tx2 = truncf(bx2), ty2 = truncf(by2);
    X1[tid] = tx1; Y1[tid] = ty1; X2[tid] = tx2; Y2[tid] = ty2;
    AR[tid] = (tx2 - tx1 + 1.0f) * (ty2 - ty1 + 1.0f);
    SUP[tid] = false;
  }
  __syncthreads();
  for (int i = 0; i < 399; ++i){
    bool alive = !SUP[i];
    if (alive && tid > i && tid < 400){
      float iw = fminf(X2[i], X2[tid]) - fmaxf(X1[i], X1[tid]) + 1.0f; iw = fmaxf(iw, 0.f);
      float ih = fminf(Y2[i], Y2[tid]) - fmaxf(Y1[i], Y1[tid]) + 1.0f; ih = fmaxf(ih, 0.f);
      float inter = iw * ih;
      float iou = inter / ((AR[i] + AR[tid]) - inter);
      if (iou > 0.6f) SUP[tid] = true;
    }
    __syncthreads();
  }
  if (tid < 400) dout[OKEEP + b*400 + tid] = SUP[tid] ? 0.f : 1.f;
}

extern "C" void kernel_launch(void* const* d_in, const int* in_sizes, int n_in,
                              void* d_out, int out_size, void* d_ws, size_t ws_size,
                              hipStream_t stream){
  const float* feat  = (const float*)d_in[0];
  const float* mdw   = (const float*)d_in[1];
  const float* mdb   = (const float*)d_in[2];
  const float* gamma = (const float*)d_in[3];
  const float* beta  = (const float*)d_in[4];
  const float* clsw  = (const float*)d_in[5];
  const float* clsb  = (const float*)d_in[6];
  const float* offw  = (const float*)d_in[7];
  const float* offb  = (const float*)d_in[8];
  float* dout = (float*)d_out;
  float* ws = (float*)d_ws;

  float* out0  = ws;                     // 7,577,600 f32
  float* wpack = out0 + 7577600;         // 2,359,296 f32
  float* hwp   = wpack + 2359296;        // 32,768
  float* hb    = hwp + 32768;            // 64
  float* bnm   = hb + 64;                // 512
  float* bnr   = bnm + 512;              // 512
  unsigned long long* keys = (unsigned long long*)(bnr + 512);  // 133,200 u64
  unsigned long long* cand = keys + 133200;                     // 133,200 u64
  unsigned long long* topk = cand + 133200;                     // 3,200 u64
  unsigned int* ccnt = (unsigned int*)(topk + 3200);            // 8 u32
  // total ws use: ~42.1 MB

  k_repack_w<<<dim3(9216), 256, 0, stream>>>(mdw, wpack);
  k_pack_heads<<<dim3(128), 256, 0, stream>>>(clsw, clsb, offw, offb, hwp, hb);
  k_conv3_mfma<<<dim3(464), 256, 0, stream>>>(feat, wpack, mdb, out0);
  k_bnstats<<<dim3(512), 256, 0, stream>>>(out0, bnm, bnr);
  k_bnrelu<<<dim3(29600), 256, 0, stream>>>(out0, bnm, bnr, gamma, beta);
  k_heads<<<dim3(232), 256, 0, stream>>>(out0, hwp, hb, dout);
  k_score<<<dim3(521), 256, 0, stream>>>(dout, keys);
  k_select<<<dim3(8), 1024, 0, stream>>>(keys, cand, ccnt);
  k_rank<<<dim3(8), 1024, 0, stream>>>(cand, ccnt, topk);
  k_nms<<<dim3(8), 512, 0, stream>>>(topk, dout);
}